// Round 1
// baseline (94.185 us; speedup 1.0000x reference)
//
#include <hip/hip_runtime.h>
#include <hip/hip_bf16.h>

// Problem: B=8192, DIM_IN=2048, DIM_OUT=512
//   hazards = relu(x @ W_h^T + b_h)            [8192,512]
//   out     = cumsum(hazards, axis=1) + (x @ W_base^T + b_base)
//
// Plan: k_cast (W f32->bf16) -> k_gemm (bf16 MFMA, bias+relu, base GEMV fused)
//       -> k_scan (per-row prefix sum + base add)

typedef __attribute__((ext_vector_type(8))) short  short8;
typedef __attribute__((ext_vector_type(4))) short  short4v;
typedef __attribute__((ext_vector_type(4))) float  float4v;
typedef __attribute__((ext_vector_type(4))) float  f32x4;

#define DIN  2048
#define DOUT 512
#define NROW 8192

static __device__ __forceinline__ unsigned short f2bf(float f) {
  union { float f; unsigned int u; } v; v.f = f;
  unsigned int u = v.u;
  unsigned int r = (u + 0x7FFFu + ((u >> 16) & 1u)) >> 16;   // round-to-nearest-even
  return (unsigned short)r;
}
static __device__ __forceinline__ float bf2f(unsigned short u) {
  union { unsigned int u; float f; } v; v.u = ((unsigned int)u) << 16;
  return v.f;
}

// ---------------- kernel 1: cast W_hazard [512][2048] f32 -> bf16 ----------
__global__ __launch_bounds__(256) void k_cast(const float* __restrict__ W,
                                              unsigned short* __restrict__ Wb) {
  size_t i = ((size_t)blockIdx.x * 256 + threadIdx.x) * 8;
  float4v a = *(const float4v*)(W + i);
  float4v b = *(const float4v*)(W + i + 4);
  unsigned short o[8] = { f2bf(a.x), f2bf(a.y), f2bf(a.z), f2bf(a.w),
                          f2bf(b.x), f2bf(b.y), f2bf(b.z), f2bf(b.w) };
  *(short8*)(Wb + i) = *(const short8*)o;
}

// ---------------- kernel 2: GEMM + bias + relu + base GEMV -----------------
// tile BM=128 x BN=128, BK=64; 256 threads = 4 waves of 64x64.
// A reg-staged from f32 x with fused bf16 convert; B reg-staged from bf16 W.
// LDS XOR-swizzle: 16B granule g of row r stored at g ^ (r&7)  (row = 128B).
__global__ __launch_bounds__(256) void k_gemm(
    const float* __restrict__ x, const unsigned short* __restrict__ Wb,
    const float* __restrict__ b_h, const float* __restrict__ w_base,
    const float* __restrict__ b_base, float* __restrict__ hz,
    float* __restrict__ base_out) {
  __shared__ unsigned short Asw[128 * 64];  // 16 KB
  __shared__ unsigned short Bsw[128 * 64];  // 16 KB
  __shared__ float WbL[DIN];                // 8 KB (base GEMV weights)

  const int tid  = threadIdx.x;
  const int lane = tid & 63;
  const int wv   = tid >> 6;
  const int wr   = wv >> 1, wc = wv & 1;
  const int bj   = blockIdx.x;          // 0..3  (N tiles)
  const int bi   = blockIdx.y;          // 0..63 (M tiles)
  const int m0   = bi * 128, n0 = bj * 128;
  const bool do_base = (bj == 0);

  if (do_base) {
    for (int i = tid; i < DIN; i += 256) WbL[i] = w_base[i];
  }

  // staging decomposition
  const int ar = tid >> 4, ap = tid & 15;  // A: 16 rows/round x 16 pieces (4 f32)
  const int br = tid >> 3, bp = tid & 7;   // B: 32 rows/round x 8 pieces (8 bf16)

  f32x4 acc[4][4];
  const f32x4 zero4 = {0.f, 0.f, 0.f, 0.f};
#pragma unroll
  for (int mi = 0; mi < 4; ++mi)
#pragma unroll
    for (int ni = 0; ni < 4; ++ni) acc[mi][ni] = zero4;

  float4v aReg[8];
  short8  bReg[4];

  auto load_tile = [&](int kt) {
    const int k0 = kt * 64;
#pragma unroll
    for (int rr = 0; rr < 8; ++rr) {
      int row = rr * 16 + ar;
      aReg[rr] = *(const float4v*)(x + (size_t)(m0 + row) * DIN + k0 + ap * 4);
    }
#pragma unroll
    for (int rr = 0; rr < 4; ++rr) {
      int n = rr * 32 + br;
      bReg[rr] = *(const short8*)(Wb + (size_t)(n0 + n) * DIN + k0 + bp * 8);
    }
  };

  load_tile(0);

  float basePart = 0.f;
  const int bRow = tid >> 1, bSeg = tid & 1;  // base GEMV: 2 threads per row

  for (int kt = 0; kt < DIN / 64; ++kt) {
    __syncthreads();  // previous compute done -> LDS free
    // write A (8 bf16x4 = b64 each), swizzled
#pragma unroll
    for (int rr = 0; rr < 8; ++rr) {
      int row = rr * 16 + ar;
      unsigned short t4[4] = { f2bf(aReg[rr].x), f2bf(aReg[rr].y),
                               f2bf(aReg[rr].z), f2bf(aReg[rr].w) };
      int off = row * 64 + ((((ap >> 1) ^ (row & 7)) << 3) | ((ap & 1) << 2));
      *(short4v*)&Asw[off] = *(const short4v*)t4;
    }
    // write B (b128 each), swizzled
#pragma unroll
    for (int rr = 0; rr < 4; ++rr) {
      int n = rr * 32 + br;
      int off = n * 64 + ((bp ^ (n & 7)) << 3);
      *(short8*)&Bsw[off] = bReg[rr];
    }
    __syncthreads();  // LDS ready

    if (kt + 1 < DIN / 64) load_tile(kt + 1);  // prefetch next tile into regs

#pragma unroll
    for (int kk = 0; kk < 2; ++kk) {
      short8 af[4], bfr[4];
#pragma unroll
      for (int mi = 0; mi < 4; ++mi) {
        int row = wr * 64 + mi * 16 + (lane & 15);
        int gr  = kk * 4 + (lane >> 4);
        af[mi] = *(const short8*)&Asw[row * 64 + ((gr ^ (row & 7)) << 3)];
      }
#pragma unroll
      for (int ni = 0; ni < 4; ++ni) {
        int col = wc * 64 + ni * 16 + (lane & 15);
        int gr  = kk * 4 + (lane >> 4);
        bfr[ni] = *(const short8*)&Bsw[col * 64 + ((gr ^ (col & 7)) << 3)];
      }
#pragma unroll
      for (int mi = 0; mi < 4; ++mi)
#pragma unroll
        for (int ni = 0; ni < 4; ++ni)
          acc[mi][ni] = __builtin_amdgcn_mfma_f32_16x16x32_bf16(
              af[mi], bfr[ni], acc[mi][ni], 0, 0, 0);
    }

    if (do_base) {  // base GEMV partial from the staged A tile (bf16, same precision)
      const int k0 = kt * 64;
      float p = 0.f;
#pragma unroll
      for (int j = 0; j < 4; ++j) {
        int gr = bSeg * 4 + j;
        const short8 v = *(const short8*)&Asw[bRow * 64 + ((gr ^ (bRow & 7)) << 3)];
#pragma unroll
        for (int e = 0; e < 8; ++e)
          p += bf2f((unsigned short)v[e]) * WbL[k0 + bSeg * 32 + j * 8 + e];
      }
      basePart += p;
    }
  }

  if (do_base) {
    float other = __shfl_xor(basePart, 1);
    float s = basePart + other;
    if ((tid & 1) == 0) base_out[m0 + (tid >> 1)] = s + b_base[0];
  }

  // epilogue: bias + relu -> hazards ws
  const int colb = n0 + wc * 64;
  float bias[4];
#pragma unroll
  for (int ni = 0; ni < 4; ++ni) bias[ni] = b_h[colb + ni * 16 + (lane & 15)];
#pragma unroll
  for (int mi = 0; mi < 4; ++mi) {
    int rowb = m0 + wr * 64 + mi * 16 + ((lane >> 4) << 2);
#pragma unroll
    for (int r = 0; r < 4; ++r) {
      float* dst = hz + (size_t)(rowb + r) * DOUT;
#pragma unroll
      for (int ni = 0; ni < 4; ++ni) {
        float z = acc[mi][ni][r] + bias[ni];
        dst[colb + ni * 16 + (lane & 15)] = fmaxf(z, 0.f);
      }
    }
  }
}

// ---------------- kernel 3: per-row inclusive scan + base ------------------
// 4 waves per block, one row per wave; lane holds 8 consecutive f32.
__global__ __launch_bounds__(256) void k_scan(const float* __restrict__ hz,
                                              const float* __restrict__ base,
                                              float* __restrict__ out) {
  const int tid  = threadIdx.x;
  const int lane = tid & 63;
  const int w    = tid >> 6;
  const int row  = blockIdx.x * 4 + w;

  const float* p = hz + (size_t)row * DOUT + lane * 8;
  float4v v0 = *(const float4v*)p;
  float4v v1 = *(const float4v*)(p + 4);

  float s0 = v0.x;
  float s1 = s0 + v0.y;
  float s2 = s1 + v0.z;
  float s3 = s2 + v0.w;
  float s4 = s3 + v1.x;
  float s5 = s4 + v1.y;
  float s6 = s5 + v1.z;
  float s7 = s6 + v1.w;

  float T = s7, sc = s7;
#pragma unroll
  for (int d = 1; d < 64; d <<= 1) {
    float t = __shfl_up(sc, d);
    if (lane >= d) sc += t;
  }
  float off = sc - T + base[row];

  float4v o0 = { s0 + off, s1 + off, s2 + off, s3 + off };
  float4v o1 = { s4 + off, s5 + off, s6 + off, s7 + off };
  float* q = out + (size_t)row * DOUT + lane * 8;
  *(float4v*)q       = o0;
  *(float4v*)(q + 4) = o1;
}

// ---------------------------------------------------------------------------
extern "C" void kernel_launch(void* const* d_in, const int* in_sizes, int n_in,
                              void* d_out, int out_size, void* d_ws, size_t ws_size,
                              hipStream_t stream) {
  const float* x   = (const float*)d_in[0];  // [8192,2048]
  const float* Wh  = (const float*)d_in[1];  // [512,2048]
  const float* bh  = (const float*)d_in[2];  // [512]
  const float* Wb0 = (const float*)d_in[3];  // [1,2048]
  const float* bb  = (const float*)d_in[4];  // [1]
  float* out = (float*)d_out;

  char* ws = (char*)d_ws;
  unsigned short* Wbf = (unsigned short*)ws;                        // 2 MiB
  float* base = (float*)(ws + 2u * 1024 * 1024);                    // 32 KiB
  float* hz   = (float*)(ws + 2u * 1024 * 1024 + 32u * 1024);       // 16 MiB

  k_cast<<<dim3((DOUT * DIN) / (256 * 8)), dim3(256), 0, stream>>>(Wh, Wbf);
  k_gemm<<<dim3(4, 64), dim3(256), 0, stream>>>(x, Wbf, bh, Wb0, bb, hz, base);
  k_scan<<<dim3(NROW / 4), dim3(256), 0, stream>>>(hz, base, out);
}

// Round 2
// 63.731 us; speedup vs baseline: 1.4779x; 1.4779x over previous
//
#include <hip/hip_runtime.h>
#include <hip/hip_bf16.h>

// Problem: B=8192, DIM_IN=2048, DIM_OUT=512
//   hazards = relu(x @ W_h^T + b_h)            [8192,512]
//   out     = cumsum(hazards, axis=1) + (x @ W_base^T + b_base)
//
// Round 2: fix occupancy. BM=BN=64, 4 waves of 32x32, grid 1024 (=4 blocks/CU,
// 4 waves/SIMD vs 1 before). XCD-chunked block swizzle for A-panel L2 reuse.

typedef __attribute__((ext_vector_type(8))) short  short8;
typedef __attribute__((ext_vector_type(4))) short  short4v;
typedef __attribute__((ext_vector_type(4))) float  float4v;
typedef __attribute__((ext_vector_type(4))) float  f32x4;

#define DIN  2048
#define DOUT 512
#define NROW 8192
#define NKT  (DIN / 64)

static __device__ __forceinline__ unsigned short f2bf(float f) {
  union { float f; unsigned int u; } v; v.f = f;
  unsigned int u = v.u;
  unsigned int r = (u + 0x7FFFu + ((u >> 16) & 1u)) >> 16;   // RNE
  return (unsigned short)r;
}
static __device__ __forceinline__ float bf2f(unsigned short u) {
  union { unsigned int u; float f; } v; v.u = ((unsigned int)u) << 16;
  return v.f;
}

// ---------------- kernel 1: cast W_hazard [512][2048] f32 -> bf16 ----------
__global__ __launch_bounds__(256) void k_cast(const float* __restrict__ W,
                                              unsigned short* __restrict__ Wb) {
  size_t i = ((size_t)blockIdx.x * 256 + threadIdx.x) * 8;
  float4v a = *(const float4v*)(W + i);
  float4v b = *(const float4v*)(W + i + 4);
  unsigned short o[8] = { f2bf(a.x), f2bf(a.y), f2bf(a.z), f2bf(a.w),
                          f2bf(b.x), f2bf(b.y), f2bf(b.z), f2bf(b.w) };
  *(short8*)(Wb + i) = *(const short8*)o;
}

// ---------------- kernel 2: GEMM + bias + relu + base GEMV -----------------
// tile 64x64, BK=64; 256 threads = 4 waves (2x2) of 32x32 output each.
// LDS XOR-swizzle: 16B granule g of row r stored at g ^ (r&7)   (row = 128B).
__global__ __launch_bounds__(256, 4) void k_gemm(
    const float* __restrict__ x, const unsigned short* __restrict__ Wb,
    const float* __restrict__ b_h, const float* __restrict__ w_base,
    const float* __restrict__ b_base, float* __restrict__ hz,
    float* __restrict__ base_out) {
  __shared__ unsigned short Asw[64 * 64];   // 8 KB
  __shared__ unsigned short Bsw[64 * 64];   // 8 KB
  __shared__ float WbL[DIN];                // 8 KB (base GEMV weights)

  const int tid  = threadIdx.x;
  const int lane = tid & 63;
  const int wv   = tid >> 6;
  const int wr   = wv >> 1, wc = wv & 1;

  // XCD-chunked bijective swizzle: nwg=1024, 8 XCDs, 128 blocks per XCD chunk.
  // Within a chunk, bj (N-tile) varies fastest -> the 8 sharers of an A-panel
  // are concurrent on one XCD.
  const int id  = blockIdx.x;
  const int swz = ((id & 7) << 7) | (id >> 3);
  const int bi  = swz >> 3;          // 0..127  M-tile
  const int bj  = swz & 7;           // 0..7    N-tile
  const int m0  = bi * 64, n0 = bj * 64;
  const bool do_base = (bj == 0);

  if (do_base) {
    for (int i = tid; i < DIN; i += 256) WbL[i] = w_base[i];
  }

  // staging: thread t -> row t>>2, 16-elem column block t&3
  const int sr = tid >> 2, sc = (tid & 3) * 16;

  f32x4 acc[2][2];
  const f32x4 zero4 = {0.f, 0.f, 0.f, 0.f};
#pragma unroll
  for (int mi = 0; mi < 2; ++mi)
#pragma unroll
    for (int ni = 0; ni < 2; ++ni) acc[mi][ni] = zero4;

  float4v aReg[4];
  short8  bReg[2];

  auto load_tile = [&](int kt) {
    const int k0 = kt * 64;
    const float* ap = x + (size_t)(m0 + sr) * DIN + k0 + sc;
#pragma unroll
    for (int p = 0; p < 4; ++p) aReg[p] = *(const float4v*)(ap + p * 4);
    const unsigned short* bp = Wb + (size_t)(n0 + sr) * DIN + k0 + sc;
    bReg[0] = *(const short8*)bp;
    bReg[1] = *(const short8*)(bp + 8);
  };

  load_tile(0);

  float basePart = 0.f;
  const int bRow = tid >> 2, bSeg = tid & 3;  // base GEMV: 4 threads per row

  for (int kt = 0; kt < NKT; ++kt) {
    __syncthreads();  // previous compute done -> LDS free
    {
      // A: convert 16 f32 -> 16 bf16, two swizzled b128 writes
      unsigned short t8[16];
#pragma unroll
      for (int p = 0; p < 4; ++p) {
        t8[p * 4 + 0] = f2bf(aReg[p].x); t8[p * 4 + 1] = f2bf(aReg[p].y);
        t8[p * 4 + 2] = f2bf(aReg[p].z); t8[p * 4 + 3] = f2bf(aReg[p].w);
      }
      const int g0 = (tid & 3) * 2;
      int offA0 = sr * 64 + (((g0)     ^ (sr & 7)) << 3);
      int offA1 = sr * 64 + (((g0 + 1) ^ (sr & 7)) << 3);
      *(short8*)&Asw[offA0] = *(const short8*)&t8[0];
      *(short8*)&Asw[offA1] = *(const short8*)&t8[8];
      // B: two swizzled b128 writes
      *(short8*)&Bsw[offA0] = bReg[0];
      *(short8*)&Bsw[offA1] = bReg[1];
    }
    __syncthreads();  // LDS ready

    if (kt + 1 < NKT) load_tile(kt + 1);  // prefetch next tile into regs

#pragma unroll
    for (int kk = 0; kk < 2; ++kk) {
      short8 af[2], bfr[2];
#pragma unroll
      for (int mi = 0; mi < 2; ++mi) {
        int row = wr * 32 + mi * 16 + (lane & 15);
        int gr  = kk * 4 + (lane >> 4);
        af[mi] = *(const short8*)&Asw[row * 64 + ((gr ^ (row & 7)) << 3)];
      }
#pragma unroll
      for (int ni = 0; ni < 2; ++ni) {
        int col = wc * 32 + ni * 16 + (lane & 15);
        int gr  = kk * 4 + (lane >> 4);
        bfr[ni] = *(const short8*)&Bsw[col * 64 + ((gr ^ (col & 7)) << 3)];
      }
#pragma unroll
      for (int mi = 0; mi < 2; ++mi)
#pragma unroll
        for (int ni = 0; ni < 2; ++ni)
          acc[mi][ni] = __builtin_amdgcn_mfma_f32_16x16x32_bf16(
              af[mi], bfr[ni], acc[mi][ni], 0, 0, 0);
    }

    if (do_base) {  // base GEMV partial from staged A tile (bf16 precision)
      const int k0 = kt * 64;
      float p = 0.f;
#pragma unroll
      for (int j = 0; j < 2; ++j) {
        int g = bSeg * 2 + j;
        const short8 v = *(const short8*)&Asw[bRow * 64 + ((g ^ (bRow & 7)) << 3)];
#pragma unroll
        for (int e = 0; e < 8; ++e)
          p += bf2f((unsigned short)v[e]) * WbL[k0 + bSeg * 16 + j * 8 + e];
      }
      basePart += p;
    }
  }

  if (do_base) {
    float s = basePart;
    s += __shfl_xor(s, 1);
    s += __shfl_xor(s, 2);
    if ((tid & 3) == 0) base_out[m0 + bRow] = s + b_base[0];
  }

  // epilogue: bias + relu -> hazards ws
  const int colb = n0 + wc * 32;
  float bias[2];
#pragma unroll
  for (int ni = 0; ni < 2; ++ni) bias[ni] = b_h[colb + ni * 16 + (lane & 15)];
#pragma unroll
  for (int mi = 0; mi < 2; ++mi) {
    int rowb = m0 + wr * 32 + mi * 16 + ((lane >> 4) << 2);
#pragma unroll
    for (int r = 0; r < 4; ++r) {
      float* dst = hz + (size_t)(rowb + r) * DOUT;
#pragma unroll
      for (int ni = 0; ni < 2; ++ni) {
        float z = acc[mi][ni][r] + bias[ni];
        dst[colb + ni * 16 + (lane & 15)] = fmaxf(z, 0.f);
      }
    }
  }
}

// ---------------- kernel 3: per-row inclusive scan + base ------------------
// 4 waves per block, one row per wave; lane holds 8 consecutive f32.
__global__ __launch_bounds__(256) void k_scan(const float* __restrict__ hz,
                                              const float* __restrict__ base,
                                              float* __restrict__ out) {
  const int tid  = threadIdx.x;
  const int lane = tid & 63;
  const int w    = tid >> 6;
  const int row  = blockIdx.x * 4 + w;

  const float* p = hz + (size_t)row * DOUT + lane * 8;
  float4v v0 = *(const float4v*)p;
  float4v v1 = *(const float4v*)(p + 4);

  float s0 = v0.x;
  float s1 = s0 + v0.y;
  float s2 = s1 + v0.z;
  float s3 = s2 + v0.w;
  float s4 = s3 + v1.x;
  float s5 = s4 + v1.y;
  float s6 = s5 + v1.z;
  float s7 = s6 + v1.w;

  float T = s7, sc = s7;
#pragma unroll
  for (int d = 1; d < 64; d <<= 1) {
    float t = __shfl_up(sc, d);
    if (lane >= d) sc += t;
  }
  float off = sc - T + base[row];

  float4v o0 = { s0 + off, s1 + off, s2 + off, s3 + off };
  float4v o1 = { s4 + off, s5 + off, s6 + off, s7 + off };
  float* q = out + (size_t)row * DOUT + lane * 8;
  *(float4v*)q       = o0;
  *(float4v*)(q + 4) = o1;
}

// ---------------------------------------------------------------------------
extern "C" void kernel_launch(void* const* d_in, const int* in_sizes, int n_in,
                              void* d_out, int out_size, void* d_ws, size_t ws_size,
                              hipStream_t stream) {
  const float* x   = (const float*)d_in[0];  // [8192,2048]
  const float* Wh  = (const float*)d_in[1];  // [512,2048]
  const float* bh  = (const float*)d_in[2];  // [512]
  const float* Wb0 = (const float*)d_in[3];  // [1,2048]
  const float* bb  = (const float*)d_in[4];  // [1]
  float* out = (float*)d_out;

  char* ws = (char*)d_ws;
  unsigned short* Wbf = (unsigned short*)ws;                        // 2 MiB
  float* base = (float*)(ws + 2u * 1024 * 1024);                    // 32 KiB
  float* hz   = (float*)(ws + 2u * 1024 * 1024 + 32u * 1024);       // 16 MiB

  k_cast<<<dim3((DOUT * DIN) / (256 * 8)), dim3(256), 0, stream>>>(Wh, Wbf);
  k_gemm<<<dim3(1024), dim3(256), 0, stream>>>(x, Wbf, bh, Wb0, bb, hz, base);
  k_scan<<<dim3(NROW / 4), dim3(256), 0, stream>>>(hz, base, out);
}